// Round 11
// baseline (296.748 us; speedup 1.0000x reference)
//
#include <hip/hip_runtime.h>

#define DIM 1024
#define NHEADS 16
#define HDIM 64
#define BATCH 4
#define SEQ 2048
#define MTOT (BATCH*SEQ)      // 8192 rows
// ATTN_SCALE * log2(e): softmax runs in exp2 domain
#define QSC 0.18033688011112042f
#define KVB 64
#define NT (SEQ/KVB)
#define PSTR_B 144            // P row stride bytes (72 elems)
#define DEFER_THR 8.0f

typedef __bf16 bf16;
typedef __bf16 bf16x8 __attribute__((ext_vector_type(8)));
typedef __bf16 bf16x4 __attribute__((ext_vector_type(4)));
typedef float  f32x4  __attribute__((ext_vector_type(4)));

static __device__ __forceinline__ bf16 f2bf(float f) {
  unsigned u = __builtin_bit_cast(unsigned, f);
  u = (u + 0x7FFFu + ((u >> 16) & 1u)) >> 16;   // RNE
  unsigned short s = (unsigned short)u;
  return __builtin_bit_cast(bf16, s);
}

static __device__ __forceinline__ float exp2g(float x) {
#if __has_builtin(__builtin_amdgcn_exp2f)
  return __builtin_amdgcn_exp2f(x);            // single v_exp_f32
#else
  float r; asm("v_exp_f32 %0, %1" : "=v"(r) : "v"(x)); return r;
#endif
}

// async global->LDS, 16B per lane, linear dest (wave base + lane*16)
#define GLD16(gp, lp) __builtin_amdgcn_global_load_lds( \
    (const __attribute__((address_space(1))) void*)(gp), \
    (__attribute__((address_space(3))) void*)(lp), 16, 0, 0)

// ---------------------------------------------------------------- fp32 -> bf16
__global__ __launch_bounds__(256) void k_cvt_x(const float* __restrict__ x,
                                               bf16* __restrict__ xb) {
  size_t i = ((size_t)blockIdx.x * 256 + threadIdx.x) * 4;
  const float4 v = *(const float4*)(x + i);
  bf16x4 o;
  o[0] = f2bf(v.x); o[1] = f2bf(v.y); o[2] = f2bf(v.z); o[3] = f2bf(v.w);
  *(bf16x4*)(xb + i) = o;
}

// ------------------------------------------- W [K=1024][C] -> Wt[C][1024] bf16
__global__ __launch_bounds__(256) void k_prep_w(const float* __restrict__ W,
                                                const float* __restrict__ sc,
                                                bf16* __restrict__ Wt,
                                                int C, int qscale) {
  __shared__ float tile[32][33];
  const int tx = threadIdx.x, ty = threadIdx.y;      // 32 x 8
  const int c0 = blockIdx.x * 32, k0 = blockIdx.y * 32;
#pragma unroll
  for (int j = 0; j < 4; ++j)
    tile[ty + 8*j][tx] = W[(size_t)(k0 + ty + 8*j) * C + (c0 + tx)];
  __syncthreads();
#pragma unroll
  for (int j = 0; j < 4; ++j) {
    int cc = c0 + ty + 8*j;
    float s = sc[cc];
    if (qscale && cc < DIM) s *= QSC;
    Wt[(size_t)cc * DIM + (k0 + tx)] = f2bf(tile[tx][ty + 8*j] * s);
  }
}

// --------------------------------------------------- qkv GEMM, 256x256 8-phase
// grid 384 = (M/256=32)x(N/256=12), XCD-chunked. 8 waves (2Mx4N), per-wave
// 128x64 out. BK=32; LDS 128KB = 2 sets x 2 K-tile slots x (A16K+B16K).
// Iter j computes K-tiles (2j,2j+1) from set j&1, stages (2j+2,2j+3) into the
// other set, 1 piece (8KB, 1 GLD16/thread) per phase. Counted vmcnt(3) gates
// at phases 3/7 only (never 0 in main loop). Row stride 64B -> b128 fragment
// reads are bank-uniform with NO swizzle; staging is linear.
__global__ __launch_bounds__(512, 2) void k_gemm256(const bf16* __restrict__ A,
                                                    const bf16* __restrict__ Bt,
                                                    bf16* __restrict__ Qb,
                                                    bf16* __restrict__ Kb,
                                                    bf16* __restrict__ Vb) {
  __shared__ __align__(16) char LS[131072];
  const int b0 = blockIdx.x;
  const int bswz = (b0 & 7) * 48 + (b0 >> 3);        // 384 % 8 == 0, bijective
  const int bm = bswz / 12, bn = bswz % 12;
  const int t = threadIdx.x;
  const int lane = t & 63, wave = t >> 6;
  const int c = lane & 15, g = lane >> 4;
  const int wr = wave >> 2, wc = wave & 3;
  // staging sources (linear): thread covers row t>>2 of a 128-row half,
  // 16B chunk t&3 within the K-tile's 64B row span
  const bf16* Asrc = A  + (size_t)(bm*256 + (t >> 2)) * DIM + (t & 3) * 8;
  const bf16* Bsrc = Bt + (size_t)(bn*256 + (t >> 2)) * DIM + (t & 3) * 8;
  // LDS read bases: A row = wr*128+qm*64+m*16+c; B row = wc*64+qn*32+n*16+c
  const int aoff = wr*8192 + c*64 + g*16;
  const int boff = 16384 + wc*4096 + c*64 + g*16;

  f32x4 acc[8][4] = {};

#define PIECE(pp, kt, dset) { \
    const int op_ = ((pp) >> 1) & 1, hf_ = (pp) & 1; \
    const bf16* s_ = (op_ ? Bsrc : Asrc) + (size_t)(hf_*128)*DIM + (kt)*32; \
    GLD16(s_, LS + (dset)*65536 + ((kt) & 1)*32768 + op_*16384 + hf_*8192 + t*16); }

  // prologue: stage K-tiles 0,1 into set 0, full drain once
#pragma unroll
  for (int p = 0; p < 8; ++p) PIECE(p, (p >> 2), 0);
  __syncthreads();

  for (int j = 0; j < 16; ++j) {
    const int s = j & 1;
    const char* sbase = LS + s*65536;
#pragma unroll
    for (int p = 0; p < 8; ++p) {
      if (j < 15) PIECE(p, 2*(j+1) + (p >> 2), s ^ 1);
      if (p == 3 || p == 7) {                        // counted gate (T4)
        asm volatile("s_waitcnt vmcnt(3)" ::: "memory");
        __builtin_amdgcn_sched_barrier(0);
      }
      __builtin_amdgcn_s_barrier();
      const int ks = p >> 2, qm = (p >> 1) & 1, qn = p & 1;
      const char* ab = sbase + ks*32768 + qm*4096 + aoff;
      const char* bb = sbase + ks*32768 + qn*2048 + boff;
      bf16x8 af[4], bfr[2];
#pragma unroll
      for (int m = 0; m < 4; ++m) af[m] = *(const bf16x8*)(ab + m*1024);
#pragma unroll
      for (int n = 0; n < 2; ++n) bfr[n] = *(const bf16x8*)(bb + n*1024);
      __builtin_amdgcn_s_setprio(1);
#pragma unroll
      for (int m = 0; m < 4; ++m)
#pragma unroll
        for (int n = 0; n < 2; ++n)
          acc[qm*4 + m][qn*2 + n] = __builtin_amdgcn_mfma_f32_16x16x32_bf16(
              af[m], bfr[n], acc[qm*4 + m][qn*2 + n], 0, 0, 0);
      __builtin_amdgcn_s_setprio(0);
      __builtin_amdgcn_s_barrier();
    }
  }
#undef PIECE
  // epilogue: scatter Q/K [b][h][n][d] bf16; V transposed -> Vt [b][h][d][n]
  const int which = (bn * 256) >> 10;                // 0=Q 1=K 2=V (256|1024)
  const int rb = bm*256 + wr*128, cb = bn*256 + wc*64;
  if (which < 2) {
    bf16* dst = which == 0 ? Qb : Kb;
#pragma unroll
    for (int n = 0; n < 4; ++n) {
      const int colg = cb + n*16 + c;
      const int h = (colg >> 6) & 15, d = colg & 63;
      const size_t hd = (size_t)h * (SEQ*HDIM) + d;
#pragma unroll
      for (int m = 0; m < 8; ++m)
#pragma unroll
        for (int r = 0; r < 4; ++r) {
          const int row = rb + m*16 + 4*g + r;
          const int bb_ = row >> 11, nt = row & 2047;
          dst[(size_t)bb_ * (NHEADS*SEQ*HDIM) + hd + (size_t)nt * HDIM] = (bf16)acc[m][n][r];
        }
    }
  } else {
#pragma unroll
    for (int n = 0; n < 4; ++n) {
      const int colg = cb + n*16 + c;
      const int h = (colg >> 6) & 15, d = colg & 63;
#pragma unroll
      for (int m = 0; m < 8; ++m) {
        const int row0 = rb + m*16 + 4*g;
        const int bb_ = row0 >> 11, nt = row0 & 2047;
        bf16x4 pk;
        pk[0] = (bf16)acc[m][n][0]; pk[1] = (bf16)acc[m][n][1];
        pk[2] = (bf16)acc[m][n][2]; pk[3] = (bf16)acc[m][n][3];
        *(bf16x4*)(Vb + ((size_t)(bb_*NHEADS + h)*HDIM + d)*SEQ + nt) = pk;
      }
    }
  }
}

// ---------------------------------------------------------------- proj GEMM
// (old 128x128 structure, MODE 1 path only: out fp32 = acc + g2*bp)
template<int MODE>
__global__ __launch_bounds__(256) void k_gemm(const bf16* __restrict__ A,
                                              const bf16* __restrict__ Bt,
                                              int nblk,
                                              float* __restrict__ outp,
                                              const float* __restrict__ g2,
                                              const float* __restrict__ bp) {
  __shared__ bf16 Als[128*32];
  __shared__ bf16 Bls[128*32];
  const int b0 = blockIdx.x;
  const int bswz = (b0 & 7) * ((int)gridDim.x >> 3) + (b0 >> 3);  // XCD chunk
  const int bm = bswz / nblk, bn = bswz % nblk;
  const int t = threadIdx.x;
  const int lane = t & 63, wave = t >> 6;
  const int c = lane & 15, g = lane >> 4;
  const int wm = (wave >> 1) * 64, wn = (wave & 1) * 64;
  const int srow = t >> 2, schunk = t & 3;
  const bf16* Ab = A  + (size_t)(bm*128) * DIM;
  const bf16* Bb = Bt + (size_t)(bn*128) * DIM;
  f32x4 acc[4][4] = {};
  for (int k0 = 0; k0 < DIM; k0 += 32) {
    __syncthreads();
#pragma unroll
    for (int i = 0; i < 2; ++i) {
      GLD16(Ab + (size_t)(i*64 + srow)*DIM + k0 + schunk*8,
            (char*)Als + i*4096 + t*16);
      GLD16(Bb + (size_t)(i*64 + srow)*DIM + k0 + schunk*8,
            (char*)Bls + i*4096 + t*16);
    }
    __syncthreads();
    bf16x8 a[4], b[4];
#pragma unroll
    for (int m = 0; m < 4; ++m)
      a[m] = *(const bf16x8*)&Als[(wm + m*16 + c)*32 + g*8];
#pragma unroll
    for (int n = 0; n < 4; ++n)
      b[n] = *(const bf16x8*)&Bls[(wn + n*16 + c)*32 + g*8];
#pragma unroll
    for (int m = 0; m < 4; ++m)
#pragma unroll
      for (int n = 0; n < 4; ++n)
        acc[m][n] = __builtin_amdgcn_mfma_f32_16x16x32_bf16(a[m], b[n], acc[m][n], 0, 0, 0);
  }
  const int cb = bn*128 + wn, rb = bm*128 + wm;
#pragma unroll
  for (int n = 0; n < 4; ++n) {
    const int col = cb + n*16 + c;
    const float bias = g2[col] * bp[col];
#pragma unroll
    for (int m = 0; m < 4; ++m)
#pragma unroll
      for (int r = 0; r < 4; ++r) {
        const int row = rb + m*16 + 4*g + r;
        outp[(size_t)row * DIM + col] = acc[m][n][r] + bias;
      }
  }
}

// ---------------------------------------------------------------- attention
// grid 512 = (B*H=64) x (N/256=8), XCD-chunked. 8 waves x 32 q-rows = 256 q.
// K/V double-buffered (2-phase prefetch, one barrier/tile). Swapped QK^T
// (S^T = mfma(K,Q)): per-lane softmax, packed b64 P-stores, l via ones-row
// MFMA (O^T row 64). Ballot-gated defer-max (THR=8).
__global__ __launch_bounds__(512, 4) void k_attn(const bf16* __restrict__ Q,
                                                 const bf16* __restrict__ K,
                                                 const bf16* __restrict__ Vt,
                                                 bf16* __restrict__ O) {
  __shared__ __align__(16) char Kls[2][KVB*128];     // 16 KB
  __shared__ __align__(16) char Vls[2][KVB*128];     // 16 KB
  __shared__ __align__(16) char Ones[16*128];        //  2 KB
  __shared__ __align__(16) char Pls[8][32*PSTR_B];   // 36 KB
  const int b0 = blockIdx.x;
  const int bid = (b0 & 7) * 64 + (b0 >> 3);         // XCD chunk (512/8=64)
  const int qt = bid & 7, bh = bid >> 3;
  const int t = threadIdx.x, wave = t >> 6, lane = t & 63;
  const int c = lane & 15, g = lane >> 4;
  const int csw = (c & 7) << 4;                      // K/V read swizzle
  char* Pw = Pls[wave];
  const bf16* Qp = Q + ((size_t)bh * SEQ + qt*256) * HDIM;
  const bf16* Kp = K + (size_t)bh * SEQ * HDIM;
  const bf16* Vh = Vt + (size_t)bh * HDIM * SEQ;     // [d][n]
  {
    unsigned fill = (t*4 < 128) ? 0x3F803F80u : 0u;  // two bf16(1.0)
    *(unsigned*)(Ones + t*4) = fill;
  }
  bf16x8 qf[2][2];
#pragma unroll
  for (int m = 0; m < 2; ++m)
#pragma unroll
    for (int kk = 0; kk < 2; ++kk)
      qf[m][kk] = *(const bf16x8*)(Qp + (size_t)(wave*32 + m*16 + c)*HDIM + kk*32 + g*8);
  f32x4 oacc[2][5] = {};                             // df=4 holds l (row 64)
  float rm[2] = {-1e30f, -1e30f};                    // per-lane: q = m*16+c

  const int srow = t >> 3, scbk = t & 7;
#define STAGE(buf, kv0) { \
  GLD16(Kp + (size_t)((kv0) + srow)*HDIM + 8*(scbk ^ (srow & 7)), Kls[buf] + t*16); \
  GLD16(Vh + (size_t)srow*SEQ + (kv0) + 8*(scbk ^ (srow & 7)), Vls[buf] + t*16); }

  STAGE(0, 0);
  __syncthreads();
  int cur = 0;
  for (int tile = 0; tile < NT; ++tile) {
    if (tile + 1 < NT) STAGE(cur ^ 1, (tile + 1)*KVB);
    f32x4 s2[4][2] = {};
#pragma unroll
    for (int kk = 0; kk < 2; ++kk)
#pragma unroll
      for (int n = 0; n < 4; ++n) {
        const bf16x8 kb = *(const bf16x8*)(Kls[cur] + (n*16 + c)*128 + ((kk*64 + 16*g) ^ csw));
#pragma unroll
        for (int m = 0; m < 2; ++m)
          s2[n][m] = __builtin_amdgcn_mfma_f32_16x16x32_bf16(kb, qf[m][kk], s2[n][m], 0, 0, 0);
      }
    float pm[2];
    bool allok = true;
#pragma unroll
    for (int m = 0; m < 2; ++m) {
      float v = s2[0][m][0];
#pragma unroll
      for (int n = 0; n < 4; ++n)
#pragma unroll
        for (int r = 0; r < 4; ++r) v = fmaxf(v, s2[n][m][r]);
      pm[m] = v;
      allok = allok && (v <= rm[m] + DEFER_THR);
    }
    if (tile == 0 || !__all((int)allok)) {
#pragma unroll
      for (int m = 0; m < 2; ++m) {
        float v = pm[m];
        v = fmaxf(v, __shfl_xor(v, 16));
        v = fmaxf(v, __shfl_xor(v, 32));
        const float mnew = fmaxf(rm[m], v);
        const float alpha = exp2g(rm[m] - mnew);
        rm[m] = mnew;
#pragma unroll
        for (int df = 0; df < 5; ++df) {
          oacc[m][df][0] *= alpha; oacc[m][df][1] *= alpha;
          oacc[m][df][2] *= alpha; oacc[m][df][3] *= alpha;
        }
      }
    }
#pragma unroll
    for (int m = 0; m < 2; ++m)
#pragma unroll
      for (int n = 0; n < 4; ++n) {
        bf16x4 pk;
#pragma unroll
        for (int r = 0; r < 4; ++r) pk[r] = (bf16)exp2g(s2[n][m][r] - rm[m]);
        *(bf16x4*)(Pw + (m*16 + c)*PSTR_B + n*32 + g*8) = pk;
      }
#pragma unroll
    for (int kf = 0; kf < 2; ++kf) {
      bf16x8 pbm[2];
#pragma unroll
      for (int m = 0; m < 2; ++m)
        pbm[m] = *(const bf16x8*)(Pw + (m*16 + c)*PSTR_B + kf*64 + 16*g);
#pragma unroll
      for (int df = 0; df < 5; ++df) {
        const bf16x8 va = (df < 4)
          ? *(const bf16x8*)(Vls[cur] + (df*16 + c)*128 + ((kf*64 + 16*g) ^ csw))
          : *(const bf16x8*)(Ones + c*128 + ((kf*64 + 16*g) ^ csw));
#pragma unroll
        for (int m = 0; m < 2; ++m)
          oacc[m][df] = __builtin_amdgcn_mfma_f32_16x16x32_bf16(va, pbm[m], oacc[m][df], 0, 0, 0);
      }
    }
    __syncthreads();
    cur ^= 1;
  }
#undef STAGE
  const int b = bh >> 4, h = bh & 15;
#pragma unroll
  for (int m = 0; m < 2; ++m) {
    const float lq = __shfl(oacc[m][4][0], c, 64);
    const float inv = 1.0f / lq;
    const int qg = qt*256 + wave*32 + m*16 + c;
    bf16* orow = O + ((size_t)b*SEQ + qg)*DIM + h*HDIM;
#pragma unroll
    for (int df = 0; df < 4; ++df)
#pragma unroll
      for (int r = 0; r < 4; ++r)
        orow[df*16 + 4*g + r] = (bf16)(oacc[m][df][r] * inv);
  }
}

// ---------------------------------------------------------------- launch
extern "C" void kernel_launch(void* const* d_in, const int* in_sizes, int n_in,
                              void* d_out, int out_size, void* d_ws, size_t ws_size,
                              hipStream_t stream) {
  const float* x    = (const float*)d_in[0];
  const float* Wqkv = (const float*)d_in[1];
  const float* g1   = (const float*)d_in[2];
  const float* Wp   = (const float*)d_in[3];
  const float* bp   = (const float*)d_in[4];
  const float* g2   = (const float*)d_in[5];
  float* out = (float*)d_out;
  char* ws = (char*)d_ws;
  bf16* xb  = (bf16*)ws;                       // 16 MiB [8192][1024]; reused as O
  bf16* Wqt = (bf16*)(ws + (16u<<20));         //  6 MiB [3072][1024]
  bf16* Wpt = (bf16*)(ws + (22u<<20));         //  2 MiB [1024][1024]
  bf16* Qb  = (bf16*)(ws + (24u<<20));         // 16 MiB [b][h][n][d]
  bf16* Kb  = (bf16*)(ws + (40u<<20));         // 16 MiB [b][h][n][d]
  bf16* Vb  = (bf16*)(ws + (56u<<20));         // 16 MiB [b][h][d][n]  (transposed)

  k_cvt_x<<<(MTOT*DIM)/1024, 256, 0, stream>>>(x, xb);
  k_prep_w<<<dim3(96, 32), dim3(32, 8), 0, stream>>>(Wqkv, g1, Wqt, 3*DIM, 1);
  k_prep_w<<<dim3(32, 32), dim3(32, 8), 0, stream>>>(Wp, g2, Wpt, DIM, 0);
  k_gemm256<<<384, 512, 0, stream>>>(xb, Wqt, Qb, Kb, Vb);
  k_attn<<<512, 512, 0, stream>>>(Qb, Kb, Vb, xb);
  k_gemm<1><<<64*8, 256, 0, stream>>>(xb, Wpt, 8, out, g2, bp);
}